// Round 9
// baseline (187.195 us; speedup 1.0000x reference)
//
#include <hip/hip_runtime.h>
#include <math.h>

// DIN fused pipeline, round 9: quarter-granularity blocks (8 blocks/CU = 32 waves).
//  prep: [blocks 0..2047] convert embT/embR/Wk f32->bf16 ; [2048..2303] q/u/targ bf16
//  B: per (batch,quarter q): rows s in [50q,50q+50), e in [32q,32q+32)
//     G: gather 64 clamped hist rows -> swizzled LDS bf16 (16 KB)
//     K: k-GEMM (MFMA), k held in 16 packed-bf16 VGPRs; hdot/tdot fused MFMA (mt==w)
//     T: barrier; overlay LDS as kT[j][e_l] (200x40 u16); predicated b16 stores
//     S: scores quarter-partial = q-slice x kT rows, ONE K=32 MFMA per j-tile,
//        accumulated into sp[b][j] via global atomicAdd (sp zeroed via memset)
//  F: masked exp, beta=0.5 norm, pred, sigmoid

#define HH 200
#define EE 128
#define KT_PITCH 40   // u16/row = 80 B: 16B-aligned rows, 2-way banks on b128 reads

typedef float fp32x4 __attribute__((ext_vector_type(4)));
typedef short bf16x8 __attribute__((ext_vector_type(8)));

static __device__ __forceinline__ unsigned short f2bf(float x) {
    unsigned u = __builtin_bit_cast(unsigned, x);
    unsigned r = (u + 0x7FFFu + ((u >> 16) & 1u)) >> 16;   // RNE
    return (unsigned short)r;
}

// ---------------- Kernel prep: table conversion + q/u/targ projection ----------------
#define N4_T 1600000   // embT float4 units (100000*64/4)
#define N4_R 16000     // embR
#define N4_K 4096      // Wk
#define N4_ALL (N4_T + N4_R + N4_K)
#define CONV_BLOCKS 2048
#define CONV_THREADS (CONV_BLOCKS * 256)

__global__ __launch_bounds__(256) void prep(
    const int* __restrict__ target, const int* __restrict__ tregion,
    const float* __restrict__ embT, const float* __restrict__ embR,
    const float* __restrict__ Wq, const float* __restrict__ Wk,
    const float* __restrict__ Wv,
    unsigned short* __restrict__ dT, unsigned short* __restrict__ dR,
    unsigned short* __restrict__ dK,
    unsigned short* __restrict__ qbf, unsigned short* __restrict__ ubf,
    unsigned short* __restrict__ tbf)
{
    const int tid = threadIdx.x;
    if (blockIdx.x < CONV_BLOCKS) {
        int idx = blockIdx.x * 256 + tid;
        for (int i = idx; i < N4_ALL; i += CONV_THREADS) {
            const float* src; unsigned short* dst;
            if (i < N4_T)             { src = embT + 4*(size_t)i;            dst = dT + 4*(size_t)i; }
            else if (i < N4_T + N4_R) { int j = i - N4_T;        src = embR + 4*(size_t)j; dst = dR + 4*(size_t)j; }
            else                      { int j = i - N4_T - N4_R; src = Wk   + 4*(size_t)j; dst = dK + 4*(size_t)j; }
            float4 v = *(const float4*)src;
            ushort4 o;
            o.x = f2bf(v.x); o.y = f2bf(v.y); o.z = f2bf(v.z); o.w = f2bf(v.w);
            *(ushort4*)dst = o;
        }
        return;
    }

    // projection role: 8 batches per block
    __shared__ float st[8][128];
    const int b0 = (blockIdx.x - CONV_BLOCKS) * 8;

    if (tid < 128) {
        int bb = tid >> 4, j = tid & 15;
        int b = b0 + bb;
        int ti = target[b], ri = tregion[b];
        *(float4*)&st[bb][j*4]      = *(const float4*)(embT + (size_t)ti*64 + j*4);
        *(float4*)&st[bb][64+j*4]   = *(const float4*)(embR + (size_t)ri*64 + j*4);
    }
    __syncthreads();

    if (tid < 128) {
        float acc[8] = {0,0,0,0,0,0,0,0};
        const float4* wr = (const float4*)(Wq + (size_t)tid*128);
        for (int e4 = 0; e4 < 32; e4++) {
            float4 w4 = wr[e4];
            #pragma unroll
            for (int bb = 0; bb < 8; bb++) {
                float4 t4 = *(const float4*)&st[bb][e4*4];
                acc[bb] += w4.x*t4.x + w4.y*t4.y + w4.z*t4.z + w4.w*t4.w;
            }
        }
        #pragma unroll
        for (int bb = 0; bb < 8; bb++) qbf[(size_t)(b0+bb)*128 + tid] = f2bf(acc[bb]);
    } else {
        int e = tid - 128;
        float acc[8] = {0,0,0,0,0,0,0,0};
        for (int f = 0; f < 128; f++) {
            float wv = Wv[(size_t)f*128 + e];
            #pragma unroll
            for (int bb = 0; bb < 8; bb++) acc[bb] += st[bb][f] * wv;
        }
        #pragma unroll
        for (int bb = 0; bb < 8; bb++) ubf[(size_t)(b0+bb)*128 + e] = f2bf(acc[bb]);
    }
    __syncthreads();
    {
        int bb = tid >> 5, x = (tid & 31) * 4;
        float4 t4 = *(const float4*)&st[bb][x];
        ushort4 o; o.x = f2bf(t4.x); o.y = f2bf(t4.y); o.z = f2bf(t4.z); o.w = f2bf(t4.w);
        *(ushort4*)&tbf[(size_t)(b0+bb)*128 + x] = o;
    }
}

// ---------------- Kernel B: quarter blocks, LDS overlay, atomic score partials ----------------
// grid 8192: b = bid>>2, q = bid&3.  LDS = 16.4 KB -> 8 blocks/CU (32 waves = cap).
__global__ __launch_bounds__(256, 8) void hist_gemm(
    const int* __restrict__ history, const int* __restrict__ hregion,
    const unsigned short* __restrict__ eT, const unsigned short* __restrict__ eR,
    const unsigned short* __restrict__ wk, const unsigned short* __restrict__ qb,
    const unsigned short* __restrict__ ub, const unsigned short* __restrict__ tb,
    float* __restrict__ scores, float* __restrict__ hdot, float* __restrict__ tdot)
{
    // phase G/K: hist[64][128] bf16, XOR-swizzled 256B rows (16384 B)
    // phase T/S: kT[200][KT_PITCH] bf16 (16000 B) -- same memory, after barrier
    __shared__ unsigned short smem[8192];

    const int bid = blockIdx.x;
    const int b = bid >> 2, qq = bid & 3;
    const int tid = threadIdx.x;
    const int lane = tid & 63, w = tid >> 6;
    const int c = lane & 15, g = lane >> 4;
    const int e0 = 8 * g;
    const int rbase = qq * 50;

    // Wk B-fragments: wave w owns k-columns h in [32w, 32w+32)
    bf16x8 wkf[2][4];
    #pragma unroll
    for (int nt = 0; nt < 2; nt++)
        #pragma unroll
        for (int kc = 0; kc < 4; kc++)
            wkf[nt][kc] = *(const bf16x8*)(wk + (size_t)(32*w + 16*nt + c)*128 + kc*32 + e0);

    // ---- Phase G: gather 64 clamped rows (4 iters x 256 threads, exact fill) ----
    #pragma unroll
    for (int it = 0; it < 4; it++) {
        int r = it*16 + (tid >> 4);
        int j = tid & 15;
        int rr = (r < 50) ? r : 49;                 // rows 50..63 duplicate row 49
        size_t rg = (size_t)b*200 + rbase + rr;
        const unsigned short* src;
        if (j < 8) { int ih = history[rg]; src = eT + (size_t)ih*64 + j*8; }
        else       { int ir = hregion[rg]; src = eR + (size_t)ir*64 + (j-8)*8; }
        unsigned dst = ((unsigned)(r*256 + j*16)) ^ (((unsigned)(r & 7)) << 4);
        *(uint4*)((char*)smem + dst) = *(const uint4*)src;
    }
    __syncthreads();

    // ---- Phase K: 4 m-tiles; k kept in 16 packed-bf16 VGPRs ----
    unsigned kv[16];
    #pragma unroll
    for (int mt = 0; mt < 4; mt++) {
        const int ar = mt*16 + c;
        const unsigned swa = ((unsigned)(ar & 7)) << 4;
        bf16x8 a[4];
        #pragma unroll
        for (int kc = 0; kc < 4; kc++) {
            unsigned off = ((unsigned)(ar*256 + kc*64 + e0*2)) ^ swa;
            a[kc] = *(const bf16x8*)((const char*)smem + off);
        }
        fp32x4 acc0 = {0,0,0,0}, acc1 = {0,0,0,0};
        #pragma unroll
        for (int kc = 0; kc < 4; kc++) {
            acc0 = __builtin_amdgcn_mfma_f32_16x16x32_bf16(a[kc], wkf[0][kc], acc0, 0, 0, 0);
            acc1 = __builtin_amdgcn_mfma_f32_16x16x32_bf16(a[kc], wkf[1][kc], acc1, 0, 0, 0);
        }
        #pragma unroll
        for (int r = 0; r < 4; r++)
            kv[mt*4 + r] = (unsigned)f2bf(acc0[r]) | ((unsigned)f2bf(acc1[r]) << 16);

        // fused hdot/tdot: extra MFMA vs [u|t] packed B (cols 0-7=u, 8-15=t); wave w owns mt=w
        if (mt == w) {
            const unsigned short* utp = (c < 8 ? ub : tb) + (size_t)b*128;
            fp32x4 hacc = {0,0,0,0};
            #pragma unroll
            for (int kc = 0; kc < 4; kc++) {
                bf16x8 utf = *(const bf16x8*)(utp + kc*32 + e0);
                hacc = __builtin_amdgcn_mfma_f32_16x16x32_bf16(a[kc], utf, hacc, 0, 0, 0);
            }
            if (c == 0 || c == 8) {
                float* dst = (c == 0) ? hdot : tdot;
                const int slb = mt*16 + 4*g;
                #pragma unroll
                for (int r = 0; r < 4; r++) {
                    int sl = slb + r;
                    if (sl < 50) dst[(size_t)b*200 + rbase + sl] = hacc[r];
                }
            }
        }
    }
    __syncthreads();   // hist tile fully consumed; smem becomes kT

    // ---- Phase T: predicated kT stores: f=200e+j, e_l = e-32q in [0,32) ----
    #pragma unroll
    for (int mt = 0; mt < 4; mt++) {
        const int slb = mt*16 + 4*g;
        #pragma unroll
        for (int r = 0; r < 4; r++) {
            int sl = slb + r;
            if (sl < 50) {
                unsigned v = kv[mt*4 + r];
                unsigned f  = (unsigned)((rbase + sl)*128 + 32*w + c);
                unsigned e  = f / 200u;  unsigned j  = f - e*200u;
                smem[j*KT_PITCH + (e - (unsigned)(qq<<5))] = (unsigned short)v;
                unsigned f2 = f + 16u;
                unsigned e2 = f2 / 200u; unsigned j2 = f2 - e2*200u;
                smem[j2*KT_PITCH + (e2 - (unsigned)(qq<<5))] = (unsigned short)(v >> 16);
            }
        }
    }
    __syncthreads();

    // ---- Phase S: quarter-partial scores, one K=32 MFMA per j-tile, atomicAdd out ----
    const bf16x8 af = *(const bf16x8*)(qb + (size_t)b*128 + (qq<<5) + e0);  // lane-invariant over jt
    for (int jt = w; jt < 13; jt += 4) {
        int jr = jt*16 + c; if (jr > 199) jr = 199;   // pad rows discarded below
        bf16x8 bfr = *(const bf16x8*)&smem[(unsigned)jr*KT_PITCH + e0];
        fp32x4 sacc = {0,0,0,0};
        sacc = __builtin_amdgcn_mfma_f32_16x16x32_bf16(af, bfr, sacc, 0, 0, 0);
        if (lane < 16) {
            int j = jt*16 + lane;
            if (j < 200) atomicAdd(&scores[(size_t)b*200 + j], sacc[0]);
        }
    }
}

// ---------------- Kernel F: finalize (8 batches/block) ----------------
__global__ __launch_bounds__(256) void finalize_k(
    const int* __restrict__ history, const int* __restrict__ target,
    const float* __restrict__ hvr,
    const float* __restrict__ scores, const float* __restrict__ hdot,
    const float* __restrict__ tdot, float* __restrict__ out)
{
    const int tid = threadIdx.x, lane = tid & 63, w = tid >> 6;
    #pragma unroll
    for (int bb = 0; bb < 2; bb++) {
        int b = blockIdx.x*8 + w*2 + bb;
        int tgt = target[b];
        float ev[4], hd[4], td[4], hv[4];
        #pragma unroll
        for (int i = 0; i < 4; i++) {
            int j = lane + i*64;
            if (j < 200) {
                float sc = scores[(size_t)b*200 + j];
                int uh = history[(size_t)b*200 + j];
                ev[i] = (uh != tgt) ? expf(sc * 0.088388347648318447f) : 0.f;
                hd[i] = hdot[(size_t)b*200 + j];
                td[i] = tdot[(size_t)b*200 + j];
                hv[i] = hvr[j];
            } else { ev[i] = 0.f; hd[i] = 0.f; td[i] = 0.f; hv[i] = 0.f; }
        }
        float tot = (ev[0]+ev[1]) + (ev[2]+ev[3]);
        #pragma unroll
        for (int m = 1; m < 64; m <<= 1) tot += __shfl_xor(tot, m, 64);
        float inv = rsqrtf(tot);          // exp_A / sum^0.5
        float p = 0.f;
        #pragma unroll
        for (int i = 0; i < 4; i++) p += ev[i]*inv*hd[i] + hv[i]*td[i];
        #pragma unroll
        for (int m = 1; m < 64; m <<= 1) p += __shfl_xor(p, m, 64);
        if (lane == 0) out[b] = 1.0f / (1.0f + expf(-p));
    }
}

extern "C" void kernel_launch(void* const* d_in, const int* in_sizes, int n_in,
                              void* d_out, int out_size, void* d_ws, size_t ws_size,
                              hipStream_t stream) {
    const int*   history = (const int*)d_in[0];
    const int*   target  = (const int*)d_in[1];
    const int*   hregion = (const int*)d_in[2];
    const int*   tregion = (const int*)d_in[3];
    const float* hvrate  = (const float*)d_in[4];
    const float* embT    = (const float*)d_in[5];
    const float* embR    = (const float*)d_in[6];
    const float* Wq      = (const float*)d_in[7];
    const float* Wk      = (const float*)d_in[8];
    const float* Wv      = (const float*)d_in[9];
    float* outp = (float*)d_out;

    char* ws = (char*)d_ws;
    unsigned short* dT = (unsigned short*)(ws);                 // 12,800,000 B
    unsigned short* dR = (unsigned short*)(ws + 12800000);      //    128,000
    unsigned short* dK = (unsigned short*)(ws + 12928000);      //     32,768
    unsigned short* ub = (unsigned short*)(ws + 12960768);      //    524,288
    unsigned short* tb = (unsigned short*)(ws + 13485056);      //    524,288
    unsigned short* qb = (unsigned short*)(ws + 14009344);      //    524,288
    float* sp          = (float*)(ws + 14533632);               //  1,638,400
    float* hdp         = (float*)(ws + 16172032);               //  1,638,400
    float* tdp         = (float*)(ws + 17810432);               //  1,638,400  (end 19,448,832)

    hipMemsetAsync(sp, 0, 1638400, stream);
    hipLaunchKernelGGL(prep, dim3(CONV_BLOCKS + 256), dim3(256), 0, stream,
                       target, tregion, embT, embR, Wq, Wk, Wv,
                       dT, dR, dK, qb, ub, tb);
    hipLaunchKernelGGL(hist_gemm, dim3(8192), dim3(256), 0, stream,
                       history, hregion, dT, dR, dK, qb, ub, tb, sp, hdp, tdp);
    hipLaunchKernelGGL(finalize_k, dim3(256), dim3(256), 0, stream,
                       history, target, hvrate, sp, hdp, tdp, outp);
}

// Round 10
// 102.713 us; speedup vs baseline: 1.8225x; 1.8225x over previous
//
#include <hip/hip_runtime.h>
#include <math.h>

// DIN fused pipeline, round 10: quarter blocks at 6 blocks/CU (no spill).
//  prep: [blocks 0..2047] convert embT/embR/Wk f32->bf16 ; [2048..2303] q/u/targ bf16
//  B: per (batch,quarter q): rows s in [50q,50q+50), e in [32q,32q+32)
//     G: gather 64 clamped hist rows -> swizzled LDS bf16 (16 KB)
//     K: k-GEMM (MFMA), k held in 16 packed-bf16 VGPRs
//     H: separate mini-pass: hdot/tdot fused MFMA for mt==w (re-reads a-frags;
//        keeps utf/hacc out of the main loop's live range -> peak VGPR < 85)
//     T: barrier; overlay LDS as kT[j][e_l] (200x40 u16); predicated b16 stores
//     S: scores quarter-partial = q-slice x kT rows, one K=32 MFMA per j-tile,
//        accumulated into sp[b][j] via global atomicAdd (sp zeroed via memset)
//  F: masked exp, beta=0.5 norm, pred, sigmoid

#define HH 200
#define EE 128
#define KT_PITCH 40   // u16/row = 80 B: 16B-aligned rows (80=5*16)

typedef float fp32x4 __attribute__((ext_vector_type(4)));
typedef short bf16x8 __attribute__((ext_vector_type(8)));

static __device__ __forceinline__ unsigned short f2bf(float x) {
    unsigned u = __builtin_bit_cast(unsigned, x);
    unsigned r = (u + 0x7FFFu + ((u >> 16) & 1u)) >> 16;   // RNE
    return (unsigned short)r;
}

// ---------------- Kernel prep: table conversion + q/u/targ projection ----------------
#define N4_T 1600000   // embT float4 units (100000*64/4)
#define N4_R 16000     // embR
#define N4_K 4096      // Wk
#define N4_ALL (N4_T + N4_R + N4_K)
#define CONV_BLOCKS 2048
#define CONV_THREADS (CONV_BLOCKS * 256)

__global__ __launch_bounds__(256) void prep(
    const int* __restrict__ target, const int* __restrict__ tregion,
    const float* __restrict__ embT, const float* __restrict__ embR,
    const float* __restrict__ Wq, const float* __restrict__ Wk,
    const float* __restrict__ Wv,
    unsigned short* __restrict__ dT, unsigned short* __restrict__ dR,
    unsigned short* __restrict__ dK,
    unsigned short* __restrict__ qbf, unsigned short* __restrict__ ubf,
    unsigned short* __restrict__ tbf)
{
    const int tid = threadIdx.x;
    if (blockIdx.x < CONV_BLOCKS) {
        int idx = blockIdx.x * 256 + tid;
        for (int i = idx; i < N4_ALL; i += CONV_THREADS) {
            const float* src; unsigned short* dst;
            if (i < N4_T)             { src = embT + 4*(size_t)i;            dst = dT + 4*(size_t)i; }
            else if (i < N4_T + N4_R) { int j = i - N4_T;        src = embR + 4*(size_t)j; dst = dR + 4*(size_t)j; }
            else                      { int j = i - N4_T - N4_R; src = Wk   + 4*(size_t)j; dst = dK + 4*(size_t)j; }
            float4 v = *(const float4*)src;
            ushort4 o;
            o.x = f2bf(v.x); o.y = f2bf(v.y); o.z = f2bf(v.z); o.w = f2bf(v.w);
            *(ushort4*)dst = o;
        }
        return;
    }

    // projection role: 8 batches per block
    __shared__ float st[8][128];
    const int b0 = (blockIdx.x - CONV_BLOCKS) * 8;

    if (tid < 128) {
        int bb = tid >> 4, j = tid & 15;
        int b = b0 + bb;
        int ti = target[b], ri = tregion[b];
        *(float4*)&st[bb][j*4]      = *(const float4*)(embT + (size_t)ti*64 + j*4);
        *(float4*)&st[bb][64+j*4]   = *(const float4*)(embR + (size_t)ri*64 + j*4);
    }
    __syncthreads();

    if (tid < 128) {
        float acc[8] = {0,0,0,0,0,0,0,0};
        const float4* wr = (const float4*)(Wq + (size_t)tid*128);
        for (int e4 = 0; e4 < 32; e4++) {
            float4 w4 = wr[e4];
            #pragma unroll
            for (int bb = 0; bb < 8; bb++) {
                float4 t4 = *(const float4*)&st[bb][e4*4];
                acc[bb] += w4.x*t4.x + w4.y*t4.y + w4.z*t4.z + w4.w*t4.w;
            }
        }
        #pragma unroll
        for (int bb = 0; bb < 8; bb++) qbf[(size_t)(b0+bb)*128 + tid] = f2bf(acc[bb]);
    } else {
        int e = tid - 128;
        float acc[8] = {0,0,0,0,0,0,0,0};
        for (int f = 0; f < 128; f++) {
            float wv = Wv[(size_t)f*128 + e];
            #pragma unroll
            for (int bb = 0; bb < 8; bb++) acc[bb] += st[bb][f] * wv;
        }
        #pragma unroll
        for (int bb = 0; bb < 8; bb++) ubf[(size_t)(b0+bb)*128 + e] = f2bf(acc[bb]);
    }
    __syncthreads();
    {
        int bb = tid >> 5, x = (tid & 31) * 4;
        float4 t4 = *(const float4*)&st[bb][x];
        ushort4 o; o.x = f2bf(t4.x); o.y = f2bf(t4.y); o.z = f2bf(t4.z); o.w = f2bf(t4.w);
        *(ushort4*)&tbf[(size_t)(b0+bb)*128 + x] = o;
    }
}

// ---------------- Kernel B: quarter blocks, 6/CU, LDS overlay, atomic partials ----------------
// grid 8192: b = bid>>2, q = bid&3.  LDS = 16.4 KB; VGPR cap 85 -> 6 blocks/CU.
__global__ __launch_bounds__(256, 6) void hist_gemm(
    const int* __restrict__ history, const int* __restrict__ hregion,
    const unsigned short* __restrict__ eT, const unsigned short* __restrict__ eR,
    const unsigned short* __restrict__ wk, const unsigned short* __restrict__ qb,
    const unsigned short* __restrict__ ub, const unsigned short* __restrict__ tb,
    float* __restrict__ scores, float* __restrict__ hdot, float* __restrict__ tdot)
{
    // phase G/K/H: hist[64][128] bf16, XOR-swizzled 256B rows (16384 B)
    // phase T/S:   kT[200][KT_PITCH] bf16 (16000 B) -- same memory, after barrier
    __shared__ unsigned short smem[8192];

    const int bid = blockIdx.x;
    const int b = bid >> 2, qq = bid & 3;
    const int tid = threadIdx.x;
    const int lane = tid & 63, w = tid >> 6;
    const int c = lane & 15, g = lane >> 4;
    const int e0 = 8 * g;
    const int rbase = qq * 50;

    // Wk B-fragments: wave w owns k-columns h in [32w, 32w+32)
    bf16x8 wkf[2][4];
    #pragma unroll
    for (int nt = 0; nt < 2; nt++)
        #pragma unroll
        for (int kc = 0; kc < 4; kc++)
            wkf[nt][kc] = *(const bf16x8*)(wk + (size_t)(32*w + 16*nt + c)*128 + kc*32 + e0);

    // ---- Phase G: gather 64 clamped rows (4 iters x 256 threads, exact fill) ----
    #pragma unroll
    for (int it = 0; it < 4; it++) {
        int r = it*16 + (tid >> 4);
        int j = tid & 15;
        int rr = (r < 50) ? r : 49;                 // rows 50..63 duplicate row 49
        size_t rg = (size_t)b*200 + rbase + rr;
        const unsigned short* src;
        if (j < 8) { int ih = history[rg]; src = eT + (size_t)ih*64 + j*8; }
        else       { int ir = hregion[rg]; src = eR + (size_t)ir*64 + (j-8)*8; }
        unsigned dst = ((unsigned)(r*256 + j*16)) ^ (((unsigned)(r & 7)) << 4);
        *(uint4*)((char*)smem + dst) = *(const uint4*)src;
    }
    __syncthreads();

    // ---- Phase K: 4 m-tiles; k kept in 16 packed-bf16 VGPRs ----
    unsigned kv[16];
    #pragma unroll
    for (int mt = 0; mt < 4; mt++) {
        const int ar = mt*16 + c;
        const unsigned swa = ((unsigned)(ar & 7)) << 4;
        bf16x8 a[4];
        #pragma unroll
        for (int kc = 0; kc < 4; kc++) {
            unsigned off = ((unsigned)(ar*256 + kc*64 + e0*2)) ^ swa;
            a[kc] = *(const bf16x8*)((const char*)smem + off);
        }
        fp32x4 acc0 = {0,0,0,0}, acc1 = {0,0,0,0};
        #pragma unroll
        for (int kc = 0; kc < 4; kc++) {
            acc0 = __builtin_amdgcn_mfma_f32_16x16x32_bf16(a[kc], wkf[0][kc], acc0, 0, 0, 0);
            acc1 = __builtin_amdgcn_mfma_f32_16x16x32_bf16(a[kc], wkf[1][kc], acc1, 0, 0, 0);
        }
        #pragma unroll
        for (int r = 0; r < 4; r++)
            kv[mt*4 + r] = (unsigned)f2bf(acc0[r]) | ((unsigned)f2bf(acc1[r]) << 16);
    }

    // ---- Phase H: hdot/tdot mini-pass (wave w handles m-tile w; a-frags re-read) ----
    {
        const int ar = w*16 + c;
        const unsigned swa = ((unsigned)(ar & 7)) << 4;
        const unsigned short* utp = (c < 8 ? ub : tb) + (size_t)b*128;
        fp32x4 hacc = {0,0,0,0};
        #pragma unroll
        for (int kc = 0; kc < 4; kc++) {
            unsigned off = ((unsigned)(ar*256 + kc*64 + e0*2)) ^ swa;
            bf16x8 av  = *(const bf16x8*)((const char*)smem + off);
            bf16x8 utf = *(const bf16x8*)(utp + kc*32 + e0);
            hacc = __builtin_amdgcn_mfma_f32_16x16x32_bf16(av, utf, hacc, 0, 0, 0);
        }
        if (c == 0 || c == 8) {
            float* dst = (c == 0) ? hdot : tdot;
            const int slb = w*16 + 4*g;
            #pragma unroll
            for (int r = 0; r < 4; r++) {
                int sl = slb + r;
                if (sl < 50) dst[(size_t)b*200 + rbase + sl] = hacc[r];
            }
        }
    }
    __syncthreads();   // hist tile fully consumed; smem becomes kT

    // ---- Phase T: predicated kT stores: f=200e+j, e_l = e-32q in [0,32) ----
    #pragma unroll
    for (int mt = 0; mt < 4; mt++) {
        const int slb = mt*16 + 4*g;
        #pragma unroll
        for (int r = 0; r < 4; r++) {
            int sl = slb + r;
            if (sl < 50) {
                unsigned v = kv[mt*4 + r];
                unsigned f  = (unsigned)((rbase + sl)*128 + 32*w + c);
                unsigned e  = f / 200u;  unsigned j  = f - e*200u;
                smem[j*KT_PITCH + (e - (unsigned)(qq<<5))] = (unsigned short)v;
                unsigned f2 = f + 16u;
                unsigned e2 = f2 / 200u; unsigned j2 = f2 - e2*200u;
                smem[j2*KT_PITCH + (e2 - (unsigned)(qq<<5))] = (unsigned short)(v >> 16);
            }
        }
    }
    __syncthreads();

    // ---- Phase S: quarter-partial scores, one K=32 MFMA per j-tile, atomicAdd out ----
    const bf16x8 af = *(const bf16x8*)(qb + (size_t)b*128 + (qq<<5) + e0);  // lane-invariant over jt
    for (int jt = w; jt < 13; jt += 4) {
        int jr = jt*16 + c; if (jr > 199) jr = 199;   // pad rows discarded below
        bf16x8 bfr = *(const bf16x8*)&smem[(unsigned)jr*KT_PITCH + e0];
        fp32x4 sacc = {0,0,0,0};
        sacc = __builtin_amdgcn_mfma_f32_16x16x32_bf16(af, bfr, sacc, 0, 0, 0);
        if (lane < 16) {
            int j = jt*16 + lane;
            if (j < 200) atomicAdd(&scores[(size_t)b*200 + j], sacc[0]);
        }
    }
}

// ---------------- Kernel F: finalize (8 batches/block) ----------------
__global__ __launch_bounds__(256) void finalize_k(
    const int* __restrict__ history, const int* __restrict__ target,
    const float* __restrict__ hvr,
    const float* __restrict__ scores, const float* __restrict__ hdot,
    const float* __restrict__ tdot, float* __restrict__ out)
{
    const int tid = threadIdx.x, lane = tid & 63, w = tid >> 6;
    #pragma unroll
    for (int bb = 0; bb < 2; bb++) {
        int b = blockIdx.x*8 + w*2 + bb;
        int tgt = target[b];
        float ev[4], hd[4], td[4], hv[4];
        #pragma unroll
        for (int i = 0; i < 4; i++) {
            int j = lane + i*64;
            if (j < 200) {
                float sc = scores[(size_t)b*200 + j];
                int uh = history[(size_t)b*200 + j];
                ev[i] = (uh != tgt) ? expf(sc * 0.088388347648318447f) : 0.f;
                hd[i] = hdot[(size_t)b*200 + j];
                td[i] = tdot[(size_t)b*200 + j];
                hv[i] = hvr[j];
            } else { ev[i] = 0.f; hd[i] = 0.f; td[i] = 0.f; hv[i] = 0.f; }
        }
        float tot = (ev[0]+ev[1]) + (ev[2]+ev[3]);
        #pragma unroll
        for (int m = 1; m < 64; m <<= 1) tot += __shfl_xor(tot, m, 64);
        float inv = rsqrtf(tot);          // exp_A / sum^0.5
        float p = 0.f;
        #pragma unroll
        for (int i = 0; i < 4; i++) p += ev[i]*inv*hd[i] + hv[i]*td[i];
        #pragma unroll
        for (int m = 1; m < 64; m <<= 1) p += __shfl_xor(p, m, 64);
        if (lane == 0) out[b] = 1.0f / (1.0f + expf(-p));
    }
}

extern "C" void kernel_launch(void* const* d_in, const int* in_sizes, int n_in,
                              void* d_out, int out_size, void* d_ws, size_t ws_size,
                              hipStream_t stream) {
    const int*   history = (const int*)d_in[0];
    const int*   target  = (const int*)d_in[1];
    const int*   hregion = (const int*)d_in[2];
    const int*   tregion = (const int*)d_in[3];
    const float* hvrate  = (const float*)d_in[4];
    const float* embT    = (const float*)d_in[5];
    const float* embR    = (const float*)d_in[6];
    const float* Wq      = (const float*)d_in[7];
    const float* Wk      = (const float*)d_in[8];
    const float* Wv      = (const float*)d_in[9];
    float* outp = (float*)d_out;

    char* ws = (char*)d_ws;
    unsigned short* dT = (unsigned short*)(ws);                 // 12,800,000 B
    unsigned short* dR = (unsigned short*)(ws + 12800000);      //    128,000
    unsigned short* dK = (unsigned short*)(ws + 12928000);      //     32,768
    unsigned short* ub = (unsigned short*)(ws + 12960768);      //    524,288
    unsigned short* tb = (unsigned short*)(ws + 13485056);      //    524,288
    unsigned short* qb = (unsigned short*)(ws + 14009344);      //    524,288
    float* sp          = (float*)(ws + 14533632);               //  1,638,400
    float* hdp         = (float*)(ws + 16172032);               //  1,638,400
    float* tdp         = (float*)(ws + 17810432);               //  1,638,400  (end 19,448,832)

    hipMemsetAsync(sp, 0, 1638400, stream);
    hipLaunchKernelGGL(prep, dim3(CONV_BLOCKS + 256), dim3(256), 0, stream,
                       target, tregion, embT, embR, Wq, Wk, Wv,
                       dT, dR, dK, qb, ub, tb);
    hipLaunchKernelGGL(hist_gemm, dim3(8192), dim3(256), 0, stream,
                       history, hregion, dT, dR, dK, qb, ub, tb, sp, hdp, tdp);
    hipLaunchKernelGGL(finalize_k, dim3(256), dim3(256), 0, stream,
                       history, target, hvrate, sp, hdp, tdp, outp);
}